// Round 2
// baseline (616.786 us; speedup 1.0000x reference)
//
#include <hip/hip_runtime.h>

// Haar DWT (stride-1, non-decimated), depthwise 2x2, right/bottom zero pad.
// x: [B, C, H, W] fp32 -> out: [B, 4*C, H, W] fp32, subbands LL,LH,HL,HH.
//
// R2 changes vs R1:
//  - 4 output rows per wave (5 input row loads) -> read amplification 1.25x, ILP 5 loads
//  - right-neighbor via __shfl_down instead of scalar global load
//  - nontemporal stores (output has zero reuse; keep L2 for input rows)

typedef float f4 __attribute__((ext_vector_type(4)));

constexpr int Bn = 8, Cn = 64, Hn = 256, Wn = 256;
constexpr int ROWS_PER_WAVE  = 4;
constexpr int WAVES_PER_BLOCK = 4;
constexpr int ROWS_PER_BLOCK = ROWS_PER_WAVE * WAVES_PER_BLOCK;  // 16

__global__ __launch_bounds__(256)
void haar_dwt_kernel(const float* __restrict__ x, float* __restrict__ out) {
    const int tid  = threadIdx.x;
    const int lane = tid & 63;
    const int wave = tid >> 6;

    const int groups = Hn / ROWS_PER_BLOCK;            // 16 row-groups per plane
    const int g  = blockIdx.x % groups;
    const int bc = blockIdx.x / groups;                // b*Cn + c
    const int row0 = g * ROWS_PER_BLOCK + wave * ROWS_PER_WAVE;
    const int j0   = lane * 4;

    const size_t plane = (size_t)Hn * Wn;
    const float* pbase = x + (size_t)bc * plane + (size_t)row0 * Wn + j0;

    // Load 5 input rows (last one zero past bottom edge), one f4 per row.
    f4 in[5];
    float e[5];
#pragma unroll
    for (int t = 0; t < 5; ++t) {
        const int r = row0 + t;
        if (r < Hn) {
            in[t] = *reinterpret_cast<const f4*>(pbase + (size_t)t * Wn);
        } else {
            in[t] = (f4){0.f, 0.f, 0.f, 0.f};
        }
        // right neighbor (element j0+4) = lane+1's first element; 0 past right edge
        const float nb = __shfl_down(in[t][0], 1, 64);
        e[t] = (lane == 63) ? 0.0f : nb;
    }

    const int b = bc / Cn;
    const int c = bc % Cn;
    float* ob = out + ((size_t)(b * 4 * Cn + 4 * c)) * plane
                    + (size_t)row0 * Wn + j0;

#pragma unroll
    for (int t = 0; t < ROWS_PER_WAVE; ++t) {
        f4 vll, vlh, vhl, vhh;
#pragma unroll
        for (int k = 0; k < 4; ++k) {
            const float x00 = in[t][k];
            const float x01 = (k < 3) ? in[t][k + 1] : e[t];
            const float x10 = in[t + 1][k];
            const float x11 = (k < 3) ? in[t + 1][k + 1] : e[t + 1];
            const float sum0 = x00 + x01;
            const float dif0 = x00 - x01;
            const float sum1 = x10 + x11;
            const float dif1 = x10 - x11;
            vll[k] = 0.5f * (sum0 + sum1);
            vlh[k] = 0.5f * (sum0 - sum1);
            vhl[k] = 0.5f * (dif0 + dif1);
            vhh[k] = 0.5f * (dif0 - dif1);
        }
        float* o = ob + (size_t)t * Wn;
        __builtin_nontemporal_store(vll, reinterpret_cast<f4*>(o));
        __builtin_nontemporal_store(vlh, reinterpret_cast<f4*>(o + plane));
        __builtin_nontemporal_store(vhl, reinterpret_cast<f4*>(o + 2 * plane));
        __builtin_nontemporal_store(vhh, reinterpret_cast<f4*>(o + 3 * plane));
    }
}

extern "C" void kernel_launch(void* const* d_in, const int* in_sizes, int n_in,
                              void* d_out, int out_size, void* d_ws, size_t ws_size,
                              hipStream_t stream) {
    const float* x = (const float*)d_in[0];
    float* out = (float*)d_out;

    const int grid = Bn * Cn * (Hn / ROWS_PER_BLOCK);  // 8*64*16 = 8192
    haar_dwt_kernel<<<grid, 256, 0, stream>>>(x, out);
}